// Round 12
// baseline (634.147 us; speedup 1.0000x reference)
//
#include <hip/hip_runtime.h>
#include <float.h>
#include <stdint.h>

#define DIM 512
#define BM 256
#define BN 128
#define BK 32
#define NSPLIT 64
#define NUM_CLASSES 1000
#define MARGIN 0.04f

typedef unsigned short ushort_t;
typedef __attribute__((ext_vector_type(4))) float fvec4;
typedef __attribute__((ext_vector_type(8))) __bf16 bvec8;
typedef __attribute__((ext_vector_type(4))) int ivec4;

#define AS1 __attribute__((address_space(1)))
#define AS3 __attribute__((address_space(3)))

__device__ inline ushort_t bf16_rne(float f) {
  uint32_t u = __builtin_bit_cast(uint32_t, f);
  uint32_t r = u + 0x7fffu + ((u >> 16) & 1u);
  return (ushort_t)(r >> 16);
}

// ---------- prep: rnorm + f32 -> bf16 (RNE) plane ----------
__global__ __launch_bounds__(256) void prep_bf16(
    const float* __restrict__ src, float* __restrict__ rnorm_out,
    ushort_t* __restrict__ hi, int rows, int scale) {
  int row = blockIdx.x * 4 + (threadIdx.x >> 6);
  int l = threadIdx.x & 63;
  if (row >= rows) return;
  const float4* p = (const float4*)(src + (size_t)row * DIM);
  float4 a = p[l * 2], b = p[l * 2 + 1];
  float rn = 1.0f;
  if (scale) {
    float s = a.x*a.x + a.y*a.y + a.z*a.z + a.w*a.w
            + b.x*b.x + b.y*b.y + b.z*b.z + b.w*b.w;
    #pragma unroll
    for (int off = 1; off < 64; off <<= 1) s += __shfl_xor(s, off, 64);
    rn = 1.0f / fmaxf(sqrtf(s), 1e-12f);
    if (rnorm_out && l == 0) rnorm_out[row] = rn;
  }
  if (!hi) return;
  float v[8] = {a.x*rn, a.y*rn, a.z*rn, a.w*rn, b.x*rn, b.y*rn, b.z*rn, b.w*rn};
  ivec4 hw;
  #pragma unroll
  for (int t = 0; t < 4; ++t) {
    ushort_t h0 = bf16_rne(v[2*t]), h1 = bf16_rne(v[2*t+1]);
    hw[t] = (int)((uint32_t)h0 | ((uint32_t)h1 << 16));
  }
  *(ivec4*)(hi + (size_t)row * DIM + l * 8) = hw;
}

// ---------- screen: bf16 MFMA GEMM; A via LDS, B DIRECT from global (L2) ----------
// R10 (validated): LDS-read-BW-bound at 96KB/CU/step. R12: B fragments are 16
// contiguous bytes/lane of pre-packed xh (brow*512+k0+lk8) -> load straight to
// VGPRs via the VMEM/L2 pipe (B panel ~1.6MB/split, L2-resident; id%8=split%8
// pins a split's m-blocks to one XCD). LDS now carries only A (32KB/CU/step)
// -> MFMA becomes the binding pipe. R11 lesson: keep total live regs < 256
// (acc 128 + A16 + B32 + keys 32 + addr ~25 ~= 235), waves_per_eu(2,2).
template <bool PRE>
__global__ __launch_bounds__(256)
__attribute__((amdgpu_waves_per_eu(2, 2)))
void nn_mfma(
    const ushort_t* __restrict__ qh, const ushort_t* __restrict__ xh,
    const float* __restrict__ qf, const float* __restrict__ xf,
    const float* __restrict__ rnorm,
    int2* __restrict__ keys, int N, int nPerSplit) {
  __shared__ __align__(1024) char smem[32768];  // 2 bufs x A(16K); B bypasses LDS
  const int tid = threadIdx.x;
  const int l = tid & 63, wv = tid >> 6;        // wave owns A rows wv*64..wv*64+63
  const int lrow = l & 15, lk8 = (l >> 4) * 8;
  const int split = blockIdx.x;
  const int m0 = blockIdx.y * BM;
  const int nStart = split * nPerSplit;
  const int nEnd = min(nStart + nPerSplit, N);

  uint32_t K1[16], K2[16];
  #pragma unroll
  for (int s = 0; s < 16; ++s) { K1[s] = 0u; K2[s] = 0u; }

  const fvec4 zero4 = {0.f, 0.f, 0.f, 0.f};

  // stage A-only (k0 step) into buffer c: 16 blobs of 1KB; wave stages 4.
  auto STAGE = [&](int c, int sk0) {
    char* base = smem + c * 16384;
    if (PRE) {
      #pragma unroll
      for (int t = 0; t < 4; ++t) {
        int f = 4 * wv + t;
        int arow = m0 + 16 * f + lrow;
        size_t aoff = (size_t)arow * DIM + sk0 + lk8;
        __builtin_amdgcn_global_load_lds((const AS1 int*)(qh + aoff), (AS3 int*)(base + f * 1024), 16, 0, 0);
      }
    } else {
      #pragma unroll
      for (int u = 0; u < 4; ++u) {
        int unit = tid + 256 * u;            // 0..1023
        int row = unit >> 2, kg = unit & 3;
        int boff_l = (row >> 4) * 1024 + kg * 256 + (row & 15) * 16;
        const float* s0 = qf + (size_t)(m0 + row) * DIM + sk0 + kg * 8;
        float4 a0 = *(const float4*)s0, a1 = *(const float4*)(s0 + 4);
        float vv[8] = {a0.x,a0.y,a0.z,a0.w,a1.x,a1.y,a1.z,a1.w};
        ivec4 hw;
        #pragma unroll
        for (int t = 0; t < 4; ++t) {
          ushort_t h0 = bf16_rne(vv[2*t]), h1 = bf16_rne(vv[2*t+1]);
          hw[t] = (int)((uint32_t)h0 | ((uint32_t)h1 << 16));
        }
        *(ivec4*)(base + boff_l) = hw;
      }
    }
  };

  int cur = 0;
  STAGE(0, 0);
  __syncthreads();   // prologue: buf0 (k0=0) ready

  #pragma unroll 1
  for (int n0 = nStart; n0 < nEnd; n0 += BN) {
    fvec4 acc[4][8];
    #pragma unroll
    for (int i = 0; i < 4; ++i)
      #pragma unroll
      for (int j = 0; j < 8; ++j) acc[i][j] = zero4;

    // per-tile B row addresses (k-invariant): rows n0+16j+lrow, clamped
    size_t brow_off[8];
    #pragma unroll
    for (int j = 0; j < 8; ++j)
      brow_off[j] = (size_t)min(n0 + 16 * j + lrow, N - 1) * DIM;

    #pragma unroll 1
    for (int k0 = 0; k0 < DIM; k0 += BK) {
      // B fragments: direct global (L2) -> VGPR, issued first to cover latency
      bvec8 Bh[8];
      if (PRE) {
        #pragma unroll
        for (int j = 0; j < 8; ++j)
          Bh[j] = __builtin_bit_cast(bvec8, *(const ivec4*)(xh + brow_off[j] + k0 + lk8));
      } else {
        #pragma unroll
        for (int j = 0; j < 8; ++j) {
          int gr = min(n0 + 16 * j + lrow, N - 1);
          float rn = rnorm[gr];
          const float* s0 = xf + brow_off[j] + k0 + lk8;
          float4 a0 = *(const float4*)s0, a1 = *(const float4*)(s0 + 4);
          float vv[8] = {a0.x*rn,a0.y*rn,a0.z*rn,a0.w*rn,a1.x*rn,a1.y*rn,a1.z*rn,a1.w*rn};
          ivec4 hw;
          #pragma unroll
          for (int t = 0; t < 4; ++t) {
            ushort_t h0 = bf16_rne(vv[2*t]), h1 = bf16_rne(vv[2*t+1]);
            hw[t] = (int)((uint32_t)h0 | ((uint32_t)h1 << 16));
          }
          Bh[j] = __builtin_bit_cast(bvec8, hw);
        }
      }

      // stage next k-step's A into the other buffer (in flight during compute)
      int next_k = k0 + BK;
      bool last_k = (next_k == DIM);
      bool more = !last_k || (n0 + BN < nEnd);
      if (more) STAGE(cur ^ 1, last_k ? 0 : next_k);

      const char* rb = smem + cur * 16384;
      bvec8 Ah[4];
      #pragma unroll
      for (int i = 0; i < 4; ++i)
        Ah[i] = __builtin_bit_cast(bvec8, *(const ivec4*)(rb + (wv*4 + i) * 1024 + l * 16));
      #pragma unroll
      for (int i = 0; i < 4; ++i)
        #pragma unroll
        for (int j = 0; j < 8; ++j)
          acc[i][j] = __builtin_amdgcn_mfma_f32_16x16x32_bf16(Ah[i], Bh[j], acc[i][j], 0, 0, 0);

      __syncthreads();  // single barrier/step: orders cur^1 A-writes vs next reads
      cur ^= 1;
    }

    // branchless in-register top-2 fold (keys: 21-bit value(+8 bias) | 11-bit inv idx)
    uint32_t msk[8], nb[8];
    #pragma unroll
    for (int j = 0; j < 8; ++j) {
      int n = n0 + j * 16 + lrow;
      bool valid = n < nEnd;
      msk[j] = valid ? 0xFFFFF800u : 0u;          // invalid -> key = 0 sentinel
      nb[j]  = valid ? (uint32_t)(2047 - (n - nStart)) : 0u;
    }
    #pragma unroll
    for (int i = 0; i < 4; ++i)
      #pragma unroll
      for (int j = 0; j < 8; ++j)
        #pragma unroll
        for (int r = 0; r < 4; ++r) {
          int s = i * 4 + r;
          uint32_t key = (__builtin_bit_cast(uint32_t, acc[i][j][r] + 8.0f) & msk[j]) | nb[j];
          uint32_t lo = min(K1[s], key);
          K1[s] = max(K1[s], key);
          K2[s] = max(K2[s], lo);
        }
  }

  // cross-lane top-2 merge over the 16 lanes sharing each query row
  #pragma unroll
  for (int s = 0; s < 16; ++s) {
    uint32_t k1 = K1[s], k2 = K2[s];
    #pragma unroll
    for (int off = 1; off < 16; off <<= 1) {
      uint32_t o1 = (uint32_t)__shfl_xor((int)k1, off, 64);
      uint32_t o2 = (uint32_t)__shfl_xor((int)k2, off, 64);
      uint32_t nk2 = max(min(k1, o1), max(k2, o2));
      k1 = max(k1, o1);
      k2 = nk2;
    }
    if (lrow == 0) {
      int m = m0 + wv * 64 + (s >> 2) * 16 + (l >> 4) * 4 + (s & 3);
      keys[(size_t)m * NSPLIT + split] = make_int2((int)k1, (int)k2);
    }
  }
}

// ---------- finalize: unpack keys, exact f32 rescore of near-max, one-hot ----------
__global__ __launch_bounds__(256) void finalize_kernel(
    const int2* __restrict__ keys,
    const float* __restrict__ qf, const float* __restrict__ xf,
    const float* __restrict__ rnorm, const int* __restrict__ y,
    int* __restrict__ out, int nPerSplit) {
  int m = blockIdx.x;
  int tid = threadIdx.x, l = tid & 63, w = tid >> 6;
  __shared__ float sv[256]; __shared__ int si[256];
  __shared__ float swm[4];
  __shared__ float swv[4]; __shared__ int swi[4];
  __shared__ int s_label;
  if (tid < 128) {
    int slot = tid >> 1;                       // = split
    int2 kk = keys[(size_t)m * NSPLIT + slot];
    uint32_t k = (tid & 1) ? (uint32_t)kk.y : (uint32_t)kk.x;
    float v; int idx;
    if (k == 0) { v = -FLT_MAX; idx = 0x7fffffff; }
    else {
      v = __builtin_bit_cast(float, k & 0xFFFFF800u) - 8.0f;
      idx = slot * nPerSplit + 2047 - (int)(k & 0x7FFu);
    }
    sv[tid] = v; si[tid] = idx;
  } else { sv[tid] = -FLT_MAX; si[tid] = 0x7fffffff; }
  __syncthreads();
  float v = sv[tid];
  #pragma unroll
  for (int off = 1; off < 64; off <<= 1) v = fmaxf(v, __shfl_xor(v, off, 64));
  if (l == 0) swm[w] = v;
  __syncthreads();
  float svmax = fmaxf(fmaxf(swm[0], swm[1]), fmaxf(swm[2], swm[3]));
  float thresh = svmax - MARGIN;
  float bestv = -FLT_MAX; int besti = 0x7fffffff;
  for (int cc = 0; cc < 64; ++cc) {
    int c = w * 64 + cc;
    float av = sv[c]; int idx = si[c];
    if (av < thresh) continue;  // wave-uniform branch
    const float4* qp = (const float4*)(qf + (size_t)m * DIM);
    const float4* xp = (const float4*)(xf + (size_t)idx * DIM);
    float s = 0.f;
    #pragma unroll
    for (int t = 0; t < 2; ++t) {
      float4 qa = qp[l * 2 + t], xa = xp[l * 2 + t];
      s += qa.x*xa.x + qa.y*xa.y + qa.z*xa.z + qa.w*xa.w;
    }
    #pragma unroll
    for (int off = 1; off < 64; off <<= 1) s += __shfl_xor(s, off, 64);
    float ev = s * rnorm[idx];
    if (ev > bestv || (ev == bestv && idx < besti)) { bestv = ev; besti = idx; }
  }
  if (l == 0) { swv[w] = bestv; swi[w] = besti; }
  __syncthreads();
  if (tid == 0) {
    float bv = swv[0]; int bi = swi[0];
    #pragma unroll
    for (int k = 1; k < 4; ++k)
      if (swv[k] > bv || (swv[k] == bv && swi[k] < bi)) { bv = swv[k]; bi = swi[k]; }
    s_label = y[bi];
  }
  __syncthreads();
  int label = s_label;
  for (int c = tid; c < NUM_CLASSES; c += 256)
    out[(size_t)m * NUM_CLASSES + c] = (c == label) ? 1 : 0;
}

extern "C" void kernel_launch(void* const* d_in, const int* in_sizes, int n_in,
                              void* d_out, int out_size, void* d_ws, size_t ws_size,
                              hipStream_t stream) {
  const float* x = (const float*)d_in[0];   // [N, 512]
  const int*   y = (const int*)d_in[1];     // [N]
  const float* q = (const float*)d_in[2];   // [M, 512]
  int N = in_sizes[0] / DIM;                // 100000
  int M = in_sizes[2] / DIM;                // 2048
  int* out = (int*)d_out;

  // workspace layout
  size_t off = 0;
  float* rnorm = (float*)((char*)d_ws + off); off += (((size_t)N * 4 + 1023) / 1024) * 1024;
  int2* keys   = (int2*)((char*)d_ws + off);  off += (size_t)M * NSPLIT * 8;
  ushort_t* qh = (ushort_t*)((char*)d_ws + off); off += (size_t)M * DIM * 2;
  ushort_t* xh = (ushort_t*)((char*)d_ws + off); off += (size_t)N * DIM * 2;
  bool pre = (ws_size >= off);

  int nPerSplit = (N + NSPLIT - 1) / NSPLIT;  // 1563 (< 2048: fits 11-bit key index)
  dim3 grid(NSPLIT, M / BM);                  // 64 x 8 = 512 blocks = 2/CU exactly

  if (pre) {
    prep_bf16<<<(N + 3) / 4, 256, 0, stream>>>(x, rnorm, xh, N, 1);
    prep_bf16<<<(M + 3) / 4, 256, 0, stream>>>(q, nullptr, qh, M, 0);
    nn_mfma<true><<<grid, 256, 0, stream>>>(qh, xh, nullptr, nullptr,
                                            rnorm, keys, N, nPerSplit);
  } else {
    prep_bf16<<<(N + 3) / 4, 256, 0, stream>>>(x, rnorm, nullptr, N, 1);
    nn_mfma<false><<<grid, 256, 0, stream>>>(nullptr, nullptr,
                                             q, x, rnorm, keys, N, nPerSplit);
  }
  finalize_kernel<<<M, 256, 0, stream>>>(keys, q, x, rnorm, y, out, nPerSplit);
}

// Round 13
// 361.864 us; speedup vs baseline: 1.7524x; 1.7524x over previous
//
#include <hip/hip_runtime.h>
#include <float.h>
#include <stdint.h>

#define DIM 512
#define BM 256
#define BN 128
#define BK 32
#define NSPLIT 64
#define NUM_CLASSES 1000
#define MARGIN 0.04f

typedef unsigned short ushort_t;
typedef __attribute__((ext_vector_type(4))) float fvec4;
typedef __attribute__((ext_vector_type(8))) __bf16 bvec8;
typedef __attribute__((ext_vector_type(4))) int ivec4;

#define AS1 __attribute__((address_space(1)))
#define AS3 __attribute__((address_space(3)))

__device__ inline ushort_t bf16_rne(float f) {
  uint32_t u = __builtin_bit_cast(uint32_t, f);
  uint32_t r = u + 0x7fffu + ((u >> 16) & 1u);
  return (ushort_t)(r >> 16);
}

// ---------- prep: rnorm + f32 -> bf16 (RNE) plane ----------
__global__ __launch_bounds__(256) void prep_bf16(
    const float* __restrict__ src, float* __restrict__ rnorm_out,
    ushort_t* __restrict__ hi, int rows, int scale) {
  int row = blockIdx.x * 4 + (threadIdx.x >> 6);
  int l = threadIdx.x & 63;
  if (row >= rows) return;
  const float4* p = (const float4*)(src + (size_t)row * DIM);
  float4 a = p[l * 2], b = p[l * 2 + 1];
  float rn = 1.0f;
  if (scale) {
    float s = a.x*a.x + a.y*a.y + a.z*a.z + a.w*a.w
            + b.x*b.x + b.y*b.y + b.z*b.z + b.w*b.w;
    #pragma unroll
    for (int off = 1; off < 64; off <<= 1) s += __shfl_xor(s, off, 64);
    rn = 1.0f / fmaxf(sqrtf(s), 1e-12f);
    if (rnorm_out && l == 0) rnorm_out[row] = rn;
  }
  if (!hi) return;
  float v[8] = {a.x*rn, a.y*rn, a.z*rn, a.w*rn, b.x*rn, b.y*rn, b.z*rn, b.w*rn};
  ivec4 hw;
  #pragma unroll
  for (int t = 0; t < 4; ++t) {
    ushort_t h0 = bf16_rne(v[2*t]), h1 = bf16_rne(v[2*t+1]);
    hw[t] = (int)((uint32_t)h0 | ((uint32_t)h1 << 16));
  }
  *(ivec4*)(hi + (size_t)row * DIM + l * 8) = hw;
}

// ---------- screen: R10 geometry + T3/T4 counted-vmcnt 3-deep pipeline ----------
// R12 post-mortem: neither LDS (235k cy) nor MFMA (258k cy) pipe saturated vs
// 845k cy runtime -> stall-bound; __syncthreads force-drains vmcnt(0) per step.
// R13: 3 staging buffers, stage(s+2) issued at step s, and the barrier becomes
// s_waitcnt vmcnt(6) + sched_barrier(0) + raw s_barrier (never drain to 0 in
// the main loop; vmcnt completes IN ORDER, so <=6 outstanding => all waves'
// stage(s+1) loads have landed). Epilogue drains with vmcnt(0). Geometry,
// blob layout, fold, keys = R10-verbatim (352us, passed).
template <bool PRE>
__global__ __launch_bounds__(256)
__attribute__((amdgpu_waves_per_eu(2, 2)))
void nn_mfma(
    const ushort_t* __restrict__ qh, const ushort_t* __restrict__ xh,
    const float* __restrict__ qf, const float* __restrict__ xf,
    const float* __restrict__ rnorm,
    int2* __restrict__ keys, int N, int nPerSplit) {
  __shared__ __align__(1024) char smem[73728];  // 3 bufs x (A 16K | B 8K)
  const int tid = threadIdx.x;
  const int l = tid & 63, wv = tid >> 6;        // wave owns rows wv*64..wv*64+63
  const int lrow = l & 15, lk8 = (l >> 4) * 8;
  const int split = blockIdx.x;
  const int m0 = blockIdx.y * BM;
  const int nStart = split * nPerSplit;
  const int nEnd = min(nStart + nPerSplit, N);
  const int nTiles = (nEnd - nStart + BN - 1) / BN;
  const int S = nTiles * 16;                    // linearized (tile, k) steps

  uint32_t K1[16], K2[16];
  #pragma unroll
  for (int s = 0; s < 16; ++s) { K1[s] = 0u; K2[s] = 0u; }

  // stage step s into buffer s%3 (A blobs 4wv..4wv+3, B blobs 2wv..2wv+1)
  auto STAGE = [&](int s) {
    char* base = smem + (s % 3) * 24576;
    int sn0 = nStart + (s >> 4) * BN;
    int sk0 = (s & 15) * BK;
    if (PRE) {
      #pragma unroll
      for (int t = 0; t < 4; ++t) {
        int f = 4 * wv + t;
        int arow = m0 + 16 * f + lrow;
        size_t aoff = (size_t)arow * DIM + sk0 + lk8;
        __builtin_amdgcn_global_load_lds((const AS1 int*)(qh + aoff), (AS3 int*)(base + f * 1024), 16, 0, 0);
      }
      #pragma unroll
      for (int t = 0; t < 2; ++t) {
        int g = 2 * wv + t;
        int brow = min(sn0 + 16 * g + lrow, N - 1);
        size_t boff = (size_t)brow * DIM + sk0 + lk8;
        __builtin_amdgcn_global_load_lds((const AS1 int*)(xh + boff), (AS3 int*)(base + 16384 + g * 1024), 16, 0, 0);
      }
    } else {
      #pragma unroll
      for (int u = 0; u < 6; ++u) {
        int unit = tid + 256 * u;            // 0..1535: A 0..1023, B 1024..1535
        if (unit < 1024) {
          int row = unit >> 2, kg = unit & 3;
          int boff_l = (row >> 4) * 1024 + kg * 256 + (row & 15) * 16;
          const float* s0 = qf + (size_t)(m0 + row) * DIM + sk0 + kg * 8;
          float4 a0 = *(const float4*)s0, a1 = *(const float4*)(s0 + 4);
          float vv[8] = {a0.x,a0.y,a0.z,a0.w,a1.x,a1.y,a1.z,a1.w};
          ivec4 hw;
          #pragma unroll
          for (int t = 0; t < 4; ++t) {
            ushort_t h0 = bf16_rne(vv[2*t]), h1 = bf16_rne(vv[2*t+1]);
            hw[t] = (int)((uint32_t)h0 | ((uint32_t)h1 << 16));
          }
          *(ivec4*)(base + boff_l) = hw;
        } else {
          int u2 = unit - 1024;
          int row = u2 >> 2, kg = u2 & 3;
          int boff_l = 16384 + (row >> 4) * 1024 + kg * 256 + (row & 15) * 16;
          int gr = min(sn0 + row, N - 1);
          float rn = rnorm[gr];
          const float* s0 = xf + (size_t)gr * DIM + sk0 + kg * 8;
          float4 a0 = *(const float4*)s0, a1 = *(const float4*)(s0 + 4);
          float vv[8] = {a0.x*rn,a0.y*rn,a0.z*rn,a0.w*rn,a1.x*rn,a1.y*rn,a1.z*rn,a1.w*rn};
          ivec4 hw;
          #pragma unroll
          for (int t = 0; t < 4; ++t) {
            ushort_t h0 = bf16_rne(vv[2*t]), h1 = bf16_rne(vv[2*t+1]);
            hw[t] = (int)((uint32_t)h0 | ((uint32_t)h1 << 16));
          }
          *(ivec4*)(base + boff_l) = hw;
        }
      }
    }
  };

  // prologue: fill pipeline 2 deep; only stage(0) must have landed
  STAGE(0);
  if (S > 1) STAGE(1);
  if (PRE) {
    asm volatile("s_waitcnt vmcnt(6)" ::: "memory");
    __builtin_amdgcn_sched_barrier(0);
    __builtin_amdgcn_s_barrier();
  } else {
    __syncthreads();
  }

  fvec4 acc[4][8];
  const fvec4 zero4 = {0.f, 0.f, 0.f, 0.f};

  #pragma unroll 1
  for (int s = 0; s < S; ++s) {
    if ((s & 15) == 0) {
      #pragma unroll
      for (int i = 0; i < 4; ++i)
        #pragma unroll
        for (int j = 0; j < 8; ++j) acc[i][j] = zero4;
    }

    if (s + 2 < S) STAGE(s + 2);   // keep 2 stages in flight

    const char* rb = smem + (s % 3) * 24576;
    bvec8 Ah[4], Bh[8];
    #pragma unroll
    for (int i = 0; i < 4; ++i)
      Ah[i] = __builtin_bit_cast(bvec8, *(const ivec4*)(rb + (wv*4 + i) * 1024 + l * 16));
    #pragma unroll
    for (int j = 0; j < 8; ++j)
      Bh[j] = __builtin_bit_cast(bvec8, *(const ivec4*)(rb + 16384 + j * 1024 + l * 16));
    #pragma unroll
    for (int i = 0; i < 4; ++i)
      #pragma unroll
      for (int j = 0; j < 8; ++j)
        acc[i][j] = __builtin_amdgcn_mfma_f32_16x16x32_bf16(Ah[i], Bh[j], acc[i][j], 0, 0, 0);

    if ((s & 15) == 15) {
      // branchless top-2 fold (keys: 21-bit value(+8 bias) | 11-bit inv idx)
      int n0 = nStart + (s >> 4) * BN;
      uint32_t msk[8], nb[8];
      #pragma unroll
      for (int j = 0; j < 8; ++j) {
        int n = n0 + j * 16 + lrow;
        bool valid = n < nEnd;
        msk[j] = valid ? 0xFFFFF800u : 0u;
        nb[j]  = valid ? (uint32_t)(2047 - (n - nStart)) : 0u;
      }
      #pragma unroll
      for (int i = 0; i < 4; ++i)
        #pragma unroll
        for (int j = 0; j < 8; ++j)
          #pragma unroll
          for (int r = 0; r < 4; ++r) {
            int ss = i * 4 + r;
            uint32_t key = (__builtin_bit_cast(uint32_t, acc[i][j][r] + 8.0f) & msk[j]) | nb[j];
            uint32_t lo = min(K1[ss], key);
            K1[ss] = max(K1[ss], key);
            K2[ss] = max(K2[ss], lo);
          }
    }

    // pipeline barrier: stage(s+1) complete (in-order vmcnt), stage(s+2) in flight
    if (PRE) {
      if (s + 2 < S) asm volatile("s_waitcnt vmcnt(6)" ::: "memory");
      else           asm volatile("s_waitcnt vmcnt(0)" ::: "memory");
      __builtin_amdgcn_sched_barrier(0);
      __builtin_amdgcn_s_barrier();
    } else {
      __syncthreads();
    }
  }

  // cross-lane top-2 merge over the 16 lanes sharing each query row
  #pragma unroll
  for (int s = 0; s < 16; ++s) {
    uint32_t k1 = K1[s], k2 = K2[s];
    #pragma unroll
    for (int off = 1; off < 16; off <<= 1) {
      uint32_t o1 = (uint32_t)__shfl_xor((int)k1, off, 64);
      uint32_t o2 = (uint32_t)__shfl_xor((int)k2, off, 64);
      uint32_t nk2 = max(min(k1, o1), max(k2, o2));
      k1 = max(k1, o1);
      k2 = nk2;
    }
    if (lrow == 0) {
      int m = m0 + wv * 64 + (s >> 2) * 16 + (l >> 4) * 4 + (s & 3);
      keys[(size_t)m * NSPLIT + split] = make_int2((int)k1, (int)k2);
    }
  }
}

// ---------- finalize: unpack keys, exact f32 rescore of near-max, one-hot ----------
__global__ __launch_bounds__(256) void finalize_kernel(
    const int2* __restrict__ keys,
    const float* __restrict__ qf, const float* __restrict__ xf,
    const float* __restrict__ rnorm, const int* __restrict__ y,
    int* __restrict__ out, int nPerSplit) {
  int m = blockIdx.x;
  int tid = threadIdx.x, l = tid & 63, w = tid >> 6;
  __shared__ float sv[256]; __shared__ int si[256];
  __shared__ float swm[4];
  __shared__ float swv[4]; __shared__ int swi[4];
  __shared__ int s_label;
  if (tid < 128) {
    int slot = tid >> 1;                       // = split
    int2 kk = keys[(size_t)m * NSPLIT + slot];
    uint32_t k = (tid & 1) ? (uint32_t)kk.y : (uint32_t)kk.x;
    float v; int idx;
    if (k == 0) { v = -FLT_MAX; idx = 0x7fffffff; }
    else {
      v = __builtin_bit_cast(float, k & 0xFFFFF800u) - 8.0f;
      idx = slot * nPerSplit + 2047 - (int)(k & 0x7FFu);
    }
    sv[tid] = v; si[tid] = idx;
  } else { sv[tid] = -FLT_MAX; si[tid] = 0x7fffffff; }
  __syncthreads();
  float v = sv[tid];
  #pragma unroll
  for (int off = 1; off < 64; off <<= 1) v = fmaxf(v, __shfl_xor(v, off, 64));
  if (l == 0) swm[w] = v;
  __syncthreads();
  float svmax = fmaxf(fmaxf(swm[0], swm[1]), fmaxf(swm[2], swm[3]));
  float thresh = svmax - MARGIN;
  float bestv = -FLT_MAX; int besti = 0x7fffffff;
  for (int cc = 0; cc < 64; ++cc) {
    int c = w * 64 + cc;
    float av = sv[c]; int idx = si[c];
    if (av < thresh) continue;  // wave-uniform branch
    const float4* qp = (const float4*)(qf + (size_t)m * DIM);
    const float4* xp = (const float4*)(xf + (size_t)idx * DIM);
    float s = 0.f;
    #pragma unroll
    for (int t = 0; t < 2; ++t) {
      float4 qa = qp[l * 2 + t], xa = xp[l * 2 + t];
      s += qa.x*xa.x + qa.y*xa.y + qa.z*xa.z + qa.w*xa.w;
    }
    #pragma unroll
    for (int off = 1; off < 64; off <<= 1) s += __shfl_xor(s, off, 64);
    float ev = s * rnorm[idx];
    if (ev > bestv || (ev == bestv && idx < besti)) { bestv = ev; besti = idx; }
  }
  if (l == 0) { swv[w] = bestv; swi[w] = besti; }
  __syncthreads();
  if (tid == 0) {
    float bv = swv[0]; int bi = swi[0];
    #pragma unroll
    for (int k = 1; k < 4; ++k)
      if (swv[k] > bv || (swv[k] == bv && swi[k] < bi)) { bv = swv[k]; bi = swi[k]; }
    s_label = y[bi];
  }
  __syncthreads();
  int label = s_label;
  for (int c = tid; c < NUM_CLASSES; c += 256)
    out[(size_t)m * NUM_CLASSES + c] = (c == label) ? 1 : 0;
}

extern "C" void kernel_launch(void* const* d_in, const int* in_sizes, int n_in,
                              void* d_out, int out_size, void* d_ws, size_t ws_size,
                              hipStream_t stream) {
  const float* x = (const float*)d_in[0];   // [N, 512]
  const int*   y = (const int*)d_in[1];     // [N]
  const float* q = (const float*)d_in[2];   // [M, 512]
  int N = in_sizes[0] / DIM;                // 100000
  int M = in_sizes[2] / DIM;                // 2048
  int* out = (int*)d_out;

  // workspace layout
  size_t off = 0;
  float* rnorm = (float*)((char*)d_ws + off); off += (((size_t)N * 4 + 1023) / 1024) * 1024;
  int2* keys   = (int2*)((char*)d_ws + off);  off += (size_t)M * NSPLIT * 8;
  ushort_t* qh = (ushort_t*)((char*)d_ws + off); off += (size_t)M * DIM * 2;
  ushort_t* xh = (ushort_t*)((char*)d_ws + off); off += (size_t)N * DIM * 2;
  bool pre = (ws_size >= off);

  int nPerSplit = (N + NSPLIT - 1) / NSPLIT;  // 1563 (< 2048: fits 11-bit key index)
  dim3 grid(NSPLIT, M / BM);                  // 64 x 8 = 512 blocks = 2/CU exactly

  if (pre) {
    prep_bf16<<<(N + 3) / 4, 256, 0, stream>>>(x, rnorm, xh, N, 1);
    prep_bf16<<<(M + 3) / 4, 256, 0, stream>>>(q, nullptr, qh, M, 0);
    nn_mfma<true><<<grid, 256, 0, stream>>>(qh, xh, nullptr, nullptr,
                                            rnorm, keys, N, nPerSplit);
  } else {
    prep_bf16<<<(N + 3) / 4, 256, 0, stream>>>(x, rnorm, nullptr, N, 1);
    nn_mfma<false><<<grid, 256, 0, stream>>>(nullptr, nullptr,
                                             q, x, rnorm, keys, N, nPerSplit);
  }
  finalize_kernel<<<M, 256, 0, stream>>>(keys, q, x, rnorm, y, out, nPerSplit);
}

// Round 14
// 315.614 us; speedup vs baseline: 2.0092x; 1.1465x over previous
//
#include <hip/hip_runtime.h>
#include <float.h>
#include <stdint.h>

#define DIM 512
#define BM 256
#define BN 256
#define NSPLIT 64
#define NUM_CLASSES 1000
#define MARGIN 0.04f

typedef unsigned short ushort_t;
typedef __attribute__((ext_vector_type(4))) float fvec4;
typedef __attribute__((ext_vector_type(8))) __bf16 bvec8;
typedef __attribute__((ext_vector_type(4))) int ivec4;

#define AS1 __attribute__((address_space(1)))
#define AS3 __attribute__((address_space(3)))

__device__ inline ushort_t bf16_rne(float f) {
  uint32_t u = __builtin_bit_cast(uint32_t, f);
  uint32_t r = u + 0x7fffu + ((u >> 16) & 1u);
  return (ushort_t)(r >> 16);
}

// ---------- prep: rnorm + f32 -> bf16 (RNE) plane ----------
__global__ __launch_bounds__(256) void prep_bf16(
    const float* __restrict__ src, float* __restrict__ rnorm_out,
    ushort_t* __restrict__ hi, int rows, int scale) {
  int row = blockIdx.x * 4 + (threadIdx.x >> 6);
  int l = threadIdx.x & 63;
  if (row >= rows) return;
  const float4* p = (const float4*)(src + (size_t)row * DIM);
  float4 a = p[l * 2], b = p[l * 2 + 1];
  float rn = 1.0f;
  if (scale) {
    float s = a.x*a.x + a.y*a.y + a.z*a.z + a.w*a.w
            + b.x*b.x + b.y*b.y + b.z*b.z + b.w*b.w;
    #pragma unroll
    for (int off = 1; off < 64; off <<= 1) s += __shfl_xor(s, off, 64);
    rn = 1.0f / fmaxf(sqrtf(s), 1e-12f);
    if (rnorm_out && l == 0) rnorm_out[row] = rn;
  }
  if (!hi) return;
  float v[8] = {a.x*rn, a.y*rn, a.z*rn, a.w*rn, b.x*rn, b.y*rn, b.z*rn, b.w*rn};
  ivec4 hw;
  #pragma unroll
  for (int t = 0; t < 4; ++t) {
    ushort_t h0 = bf16_rne(v[2*t]), h1 = bf16_rne(v[2*t+1]);
    hw[t] = (int)((uint32_t)h0 | ((uint32_t)h1 << 16));
  }
  *(ivec4*)(hi + (size_t)row * DIM + l * 8) = hw;
}

// ---------- screen (main): 8-wave 256x256 tile, phase-interleaved schedule ----------
// R13 post-mortem: 2-barrier lockstep = pipes alternate (MFMA 27%, LDS 28%, rest
// stall). This is the guide's T3+T4 regime gate: counted vmcnt pays only with a
// phase-split schedule. Port of the 8-phase idea onto our blob layout:
//  - 4 half-buffers x 32KB (half = 256 rows A + 256 rows B, K=32 chunk, 32 blobs)
//  - per half: 2 phases; phase0: {vmcnt(8)+s_barrier (fused asm), read B8+A2,
//    stage 2, setprio(1), 16 MFMA}; phase1: {read A2, stage 2, setprio(1), 16 MFMA}
//  - staging runs 3 halves ahead, 4 loads/wave/half -> vmcnt(8) leaves 2 in flight
//  - tail stages clamp to last half: idempotent same-src/same-dst rewrites (safe)
// Safety: a wave's ds_reads are lgkm-consumed before it reaches the next barrier;
// stages for a buffer issue only after the barrier retiring that buffer's readers.
__global__ __launch_bounds__(512)
__attribute__((amdgpu_waves_per_eu(2, 2)))
void nn_mfma8(
    const ushort_t* __restrict__ qh, const ushort_t* __restrict__ xh,
    int2* __restrict__ keys, int N, int nPerSplit) {
  __shared__ __align__(1024) char smem[131072];   // 4 half-buffers x 32KB
  const int tid = threadIdx.x;
  const int l = tid & 63, w = tid >> 6;           // 8 waves
  const int wm = w >> 1, wn = w & 1;              // 4M x 2N; wave tile 64 x 128
  const int lrow = l & 15, lk8 = (l >> 4) * 8;
  const int split = blockIdx.x;
  const int m0 = blockIdx.y * BM;
  const int nStart = split * nPerSplit;
  const int nEnd = min(nStart + nPerSplit, N);
  const int nTiles = (nEnd - nStart + 255) >> 8;
  const int nH = nTiles * 16;                     // 16 K-halves per 256-wide n-tile

  uint32_t K1[16], K2[16];
  #pragma unroll
  for (int s = 0; s < 16; ++s) { K1[s] = 0u; K2[s] = 0u; }

  // stage 2 blobs (part q) of half Hs; blob b: 0..15 = A, 16..31 = B; dest = base + b*1KB
  auto STAGE2 = [&](int Hs, int q) {
    Hs = min(Hs, nH - 1);
    char* base = smem + (Hs & 3) * 32768;
    int k0 = (Hs & 15) * 32;
    int sn0 = nStart + ((Hs >> 4) << 8);
    #pragma unroll
    for (int t = 0; t < 2; ++t) {
      int b = 4 * w + 2 * q + t;
      size_t off;
      const ushort_t* src;
      if (b < 16) { src = qh; off = (size_t)(m0 + 16 * b + lrow) * DIM + k0 + lk8; }
      else        { src = xh; off = (size_t)min(sn0 + 16 * (b - 16) + lrow, N - 1) * DIM + k0 + lk8; }
      __builtin_amdgcn_global_load_lds((const AS1 int*)(src + off), (AS3 int*)(base + b * 1024), 16, 0, 0);
    }
  };

  // prologue: 3 halves in flight (12 loads/wave)
  STAGE2(0, 0); STAGE2(0, 1);
  STAGE2(1, 0); STAGE2(1, 1);
  STAGE2(2, 0); STAGE2(2, 1);

  fvec4 acc[4][8];
  const fvec4 zero4 = {0.f, 0.f, 0.f, 0.f};

  #pragma unroll 1
  for (int H = 0; H < nH; ++H) {
    if ((H & 15) == 0) {
      #pragma unroll
      for (int i = 0; i < 4; ++i)
        #pragma unroll
        for (int j = 0; j < 8; ++j) acc[i][j] = zero4;
    }
    const char* rb = smem + (H & 3) * 32768;

    // ---- phase 0: counted-vmcnt barrier, B(8)+A(2) reads, stage 2, 16 MFMA ----
    asm volatile("s_waitcnt vmcnt(8)\n\ts_barrier" ::: "memory");
    __builtin_amdgcn_sched_barrier(0);
    bvec8 Bf[8];
    #pragma unroll
    for (int j = 0; j < 8; ++j)
      Bf[j] = __builtin_bit_cast(bvec8, *(const ivec4*)(rb + 16384 + (wn * 8 + j) * 1024 + l * 16));
    bvec8 A0 = __builtin_bit_cast(bvec8, *(const ivec4*)(rb + (wm * 4 + 0) * 1024 + l * 16));
    bvec8 A1 = __builtin_bit_cast(bvec8, *(const ivec4*)(rb + (wm * 4 + 1) * 1024 + l * 16));
    STAGE2(H + 3, 0);
    __builtin_amdgcn_s_setprio(1);
    #pragma unroll
    for (int j = 0; j < 8; ++j)
      acc[0][j] = __builtin_amdgcn_mfma_f32_16x16x32_bf16(A0, Bf[j], acc[0][j], 0, 0, 0);
    #pragma unroll
    for (int j = 0; j < 8; ++j)
      acc[1][j] = __builtin_amdgcn_mfma_f32_16x16x32_bf16(A1, Bf[j], acc[1][j], 0, 0, 0);
    __builtin_amdgcn_s_setprio(0);

    // ---- phase 1: A(2) reads (B reused in regs), stage 2, 16 MFMA ----
    bvec8 A2 = __builtin_bit_cast(bvec8, *(const ivec4*)(rb + (wm * 4 + 2) * 1024 + l * 16));
    bvec8 A3 = __builtin_bit_cast(bvec8, *(const ivec4*)(rb + (wm * 4 + 3) * 1024 + l * 16));
    STAGE2(H + 3, 1);
    __builtin_amdgcn_s_setprio(1);
    #pragma unroll
    for (int j = 0; j < 8; ++j)
      acc[2][j] = __builtin_amdgcn_mfma_f32_16x16x32_bf16(A2, Bf[j], acc[2][j], 0, 0, 0);
    #pragma unroll
    for (int j = 0; j < 8; ++j)
      acc[3][j] = __builtin_amdgcn_mfma_f32_16x16x32_bf16(A3, Bf[j], acc[3][j], 0, 0, 0);
    __builtin_amdgcn_s_setprio(0);

    // ---- end of n-tile: branchless top-2 fold ----
    if ((H & 15) == 15) {
      int n0 = nStart + ((H >> 4) << 8);
      uint32_t msk[8], nb[8];
      #pragma unroll
      for (int j = 0; j < 8; ++j) {
        int n = n0 + wn * 128 + j * 16 + lrow;
        bool valid = n < nEnd;
        msk[j] = valid ? 0xFFFFF800u : 0u;
        nb[j]  = valid ? (uint32_t)(2047 - (n - nStart)) : 0u;
      }
      #pragma unroll
      for (int i = 0; i < 4; ++i)
        #pragma unroll
        for (int j = 0; j < 8; ++j)
          #pragma unroll
          for (int r = 0; r < 4; ++r) {
            int ss = i * 4 + r;
            uint32_t key = (__builtin_bit_cast(uint32_t, acc[i][j][r] + 8.0f) & msk[j]) | nb[j];
            uint32_t lo = min(K1[ss], key);
            K1[ss] = max(K1[ss], key);
            K2[ss] = max(K2[ss], lo);
          }
    }
  }

  // cross-lane top-2 merge over the 16 lanes sharing each query row
  #pragma unroll
  for (int s = 0; s < 16; ++s) {
    uint32_t k1 = K1[s], k2 = K2[s];
    #pragma unroll
    for (int off = 1; off < 16; off <<= 1) {
      uint32_t o1 = (uint32_t)__shfl_xor((int)k1, off, 64);
      uint32_t o2 = (uint32_t)__shfl_xor((int)k2, off, 64);
      uint32_t nk2 = max(min(k1, o1), max(k2, o2));
      k1 = max(k1, o1);
      k2 = nk2;
    }
    if (lrow == 0) {
      int m = m0 + wm * 64 + (s >> 2) * 16 + (l >> 4) * 4 + (s & 3);
      keys[((size_t)m * NSPLIT + split) * 2 + wn] = make_int2((int)k1, (int)k2);
    }
  }
}

// ---------- fallback (no-ws path): R13 structure, f32 on-the-fly ----------
__global__ __launch_bounds__(256)
__attribute__((amdgpu_waves_per_eu(2, 2)))
void nn_mfma_fb(
    const float* __restrict__ qf, const float* __restrict__ xf,
    const float* __restrict__ rnorm,
    int2* __restrict__ keys, int N, int nPerSplit) {
  __shared__ __align__(1024) char smem[49152];
  const int tid = threadIdx.x;
  const int l = tid & 63, wv = tid >> 6;
  const int lrow = l & 15;
  const int split = blockIdx.x;
  const int m0 = blockIdx.y * BM;
  const int nStart = split * nPerSplit;
  const int nEnd = min(nStart + nPerSplit, N);

  uint32_t K1[16], K2[16];
  #pragma unroll
  for (int s = 0; s < 16; ++s) { K1[s] = 0u; K2[s] = 0u; }
  const fvec4 zero4 = {0.f, 0.f, 0.f, 0.f};

  auto STAGE = [&](int c, int sn0, int sk0) {
    char* base = smem + c * 24576;
    #pragma unroll
    for (int u = 0; u < 6; ++u) {
      int unit = tid + 256 * u;
      if (unit < 1024) {
        int row = unit >> 2, kg = unit & 3;
        int boff_l = (row >> 4) * 1024 + kg * 256 + (row & 15) * 16;
        const float* s0 = qf + (size_t)(m0 + row) * DIM + sk0 + kg * 8;
        float4 a0 = *(const float4*)s0, a1 = *(const float4*)(s0 + 4);
        float vv[8] = {a0.x,a0.y,a0.z,a0.w,a1.x,a1.y,a1.z,a1.w};
        ivec4 hw;
        #pragma unroll
        for (int t = 0; t < 4; ++t) {
          ushort_t h0 = bf16_rne(vv[2*t]), h1 = bf16_rne(vv[2*t+1]);
          hw[t] = (int)((uint32_t)h0 | ((uint32_t)h1 << 16));
        }
        *(ivec4*)(base + boff_l) = hw;
      } else {
        int u2 = unit - 1024;
        int row = u2 >> 2, kg = u2 & 3;
        int boff_l = 16384 + (row >> 4) * 1024 + kg * 256 + (row & 15) * 16;
        int gr = min(nStart == sn0 ? sn0 + row : sn0 + row, N - 1);
        gr = min(sn0 + row, N - 1);
        float rn = rnorm[gr];
        const float* s0 = xf + (size_t)gr * DIM + sk0 + kg * 8;
        float4 a0 = *(const float4*)s0, a1 = *(const float4*)(s0 + 4);
        float vv[8] = {a0.x*rn,a0.y*rn,a0.z*rn,a0.w*rn,a1.x*rn,a1.y*rn,a1.z*rn,a1.w*rn};
        ivec4 hw;
        #pragma unroll
        for (int t = 0; t < 4; ++t) {
          ushort_t h0 = bf16_rne(vv[2*t]), h1 = bf16_rne(vv[2*t+1]);
          hw[t] = (int)((uint32_t)h0 | ((uint32_t)h1 << 16));
        }
        *(ivec4*)(base + boff_l) = hw;
      }
    }
  };

  const int nTiles = (nEnd - nStart + 127) >> 7;
  const int S = nTiles * 16;
  STAGE(0, nStart, 0);
  if (S > 1) STAGE(1 % 3, nStart + ((1 >> 4) * 128), (1 & 15) * 32);
  __syncthreads();

  fvec4 acc[4][8];
  #pragma unroll 1
  for (int s = 0; s < S; ++s) {
    if ((s & 15) == 0) {
      #pragma unroll
      for (int i = 0; i < 4; ++i)
        #pragma unroll
        for (int j = 0; j < 8; ++j) acc[i][j] = zero4;
    }
    if (s + 2 < S) STAGE((s + 2) % 3, nStart + (((s + 2) >> 4) * 128), ((s + 2) & 15) * 32);
    const char* rb = smem + (s % 3) * 24576;
    bvec8 Ah[4], Bh[8];
    #pragma unroll
    for (int i = 0; i < 4; ++i)
      Ah[i] = __builtin_bit_cast(bvec8, *(const ivec4*)(rb + (wv*4 + i) * 1024 + l * 16));
    #pragma unroll
    for (int j = 0; j < 8; ++j)
      Bh[j] = __builtin_bit_cast(bvec8, *(const ivec4*)(rb + 16384 + (j >> 1) * 1024 + (j & 1) * 0 + j * 0 + j * 0 + l * 16));
    // NOTE: fallback B region has 8 blobs of 1KB starting at 16384
    #pragma unroll
    for (int j = 0; j < 8; ++j)
      Bh[j] = __builtin_bit_cast(bvec8, *(const ivec4*)(rb + 16384 + j * 1024 + l * 16));
    #pragma unroll
    for (int i = 0; i < 4; ++i)
      #pragma unroll
      for (int j = 0; j < 8; ++j)
        acc[i][j] = __builtin_amdgcn_mfma_f32_16x16x32_bf16(Ah[i], Bh[j], acc[i][j], 0, 0, 0);
    if ((s & 15) == 15) {
      int n0 = nStart + ((s >> 4) * 128);
      uint32_t msk[8], nb[8];
      #pragma unroll
      for (int j = 0; j < 8; ++j) {
        int n = n0 + j * 16 + lrow;
        bool valid = n < nEnd;
        msk[j] = valid ? 0xFFFFF800u : 0u;
        nb[j]  = valid ? (uint32_t)(2047 - (n - nStart)) : 0u;
      }
      #pragma unroll
      for (int i = 0; i < 4; ++i)
        #pragma unroll
        for (int j = 0; j < 8; ++j)
          #pragma unroll
          for (int r = 0; r < 4; ++r) {
            int ss = i * 4 + r;
            uint32_t key = (__builtin_bit_cast(uint32_t, acc[i][j][r] + 8.0f) & msk[j]) | nb[j];
            uint32_t lo = min(K1[ss], key);
            K1[ss] = max(K1[ss], key);
            K2[ss] = max(K2[ss], lo);
          }
    }
    __syncthreads();
  }

  #pragma unroll
  for (int s = 0; s < 16; ++s) {
    uint32_t k1 = K1[s], k2 = K2[s];
    #pragma unroll
    for (int off = 1; off < 16; off <<= 1) {
      uint32_t o1 = (uint32_t)__shfl_xor((int)k1, off, 64);
      uint32_t o2 = (uint32_t)__shfl_xor((int)k2, off, 64);
      uint32_t nk2 = max(min(k1, o1), max(k2, o2));
      k1 = max(k1, o1);
      k2 = nk2;
    }
    if (lrow == 0) {
      int m = m0 + wv * 64 + (s >> 2) * 16 + (l >> 4) * 4 + (s & 3);
      keys[((size_t)m * NSPLIT + split) * 2 + 0] = make_int2((int)k1, (int)k2);
      keys[((size_t)m * NSPLIT + split) * 2 + 1] = make_int2(0, 0);
    }
  }
}

// ---------- finalize: unpack 256 candidate slots, exact f32 rescore, one-hot ----------
__global__ __launch_bounds__(256) void finalize_kernel(
    const int2* __restrict__ keys,
    const float* __restrict__ qf, const float* __restrict__ xf,
    const float* __restrict__ rnorm, const int* __restrict__ y,
    int* __restrict__ out, int nPerSplit) {
  int m = blockIdx.x;
  int tid = threadIdx.x, l = tid & 63, w = tid >> 6;
  __shared__ float sv[256]; __shared__ int si[256];
  __shared__ float swm[4];
  __shared__ float swv[4]; __shared__ int swi[4];
  __shared__ int s_label;
  {
    int slot = tid >> 1;                       // split*2 + wn
    int2 kk = keys[(size_t)m * 128 + slot];
    uint32_t k = (tid & 1) ? (uint32_t)kk.y : (uint32_t)kk.x;
    float v; int idx;
    if (k == 0) { v = -FLT_MAX; idx = 0x7fffffff; }
    else {
      v = __builtin_bit_cast(float, k & 0xFFFFF800u) - 8.0f;
      idx = (slot >> 1) * nPerSplit + 2047 - (int)(k & 0x7FFu);
    }
    sv[tid] = v; si[tid] = idx;
  }
  __syncthreads();
  float v = sv[tid];
  #pragma unroll
  for (int off = 1; off < 64; off <<= 1) v = fmaxf(v, __shfl_xor(v, off, 64));
  if (l == 0) swm[w] = v;
  __syncthreads();
  float svmax = fmaxf(fmaxf(swm[0], swm[1]), fmaxf(swm[2], swm[3]));
  float thresh = svmax - MARGIN;
  float bestv = -FLT_MAX; int besti = 0x7fffffff;
  for (int cc = 0; cc < 64; ++cc) {
    int c = w * 64 + cc;
    float av = sv[c]; int idx = si[c];
    if (av < thresh) continue;  // wave-uniform branch
    const float4* qp = (const float4*)(qf + (size_t)m * DIM);
    const float4* xp = (const float4*)(xf + (size_t)idx * DIM);
    float s = 0.f;
    #pragma unroll
    for (int t = 0; t < 2; ++t) {
      float4 qa = qp[l * 2 + t], xa = xp[l * 2 + t];
      s += qa.x*xa.x + qa.y*xa.y + qa.z*xa.z + qa.w*xa.w;
    }
    #pragma unroll
    for (int off = 1; off < 64; off <<= 1) s += __shfl_xor(s, off, 64);
    float ev = s * rnorm[idx];
    if (ev > bestv || (ev == bestv && idx < besti)) { bestv = ev; besti = idx; }
  }
  if (l == 0) { swv[w] = bestv; swi[w] = besti; }
  __syncthreads();
  if (tid == 0) {
    float bv = swv[0]; int bi = swi[0];
    #pragma unroll
    for (int k = 1; k < 4; ++k)
      if (swv[k] > bv || (swv[k] == bv && swi[k] < bi)) { bv = swv[k]; bi = swi[k]; }
    s_label = y[bi];
  }
  __syncthreads();
  int label = s_label;
  for (int c = tid; c < NUM_CLASSES; c += 256)
    out[(size_t)m * NUM_CLASSES + c] = (c == label) ? 1 : 0;
}

extern "C" void kernel_launch(void* const* d_in, const int* in_sizes, int n_in,
                              void* d_out, int out_size, void* d_ws, size_t ws_size,
                              hipStream_t stream) {
  const float* x = (const float*)d_in[0];   // [N, 512]
  const int*   y = (const int*)d_in[1];     // [N]
  const float* q = (const float*)d_in[2];   // [M, 512]
  int N = in_sizes[0] / DIM;                // 100000
  int M = in_sizes[2] / DIM;                // 2048
  int* out = (int*)d_out;

  // workspace layout
  size_t off = 0;
  float* rnorm = (float*)((char*)d_ws + off); off += (((size_t)N * 4 + 1023) / 1024) * 1024;
  int2* keys   = (int2*)((char*)d_ws + off);  off += (size_t)M * NSPLIT * 2 * 8;
  ushort_t* qh = (ushort_t*)((char*)d_ws + off); off += (size_t)M * DIM * 2;
  ushort_t* xh = (ushort_t*)((char*)d_ws + off); off += (size_t)N * DIM * 2;
  bool pre = (ws_size >= off);

  int nPerSplit = (N + NSPLIT - 1) / NSPLIT;  // 1563 (< 2048: fits 11-bit key index)

  if (pre) {
    prep_bf16<<<(N + 3) / 4, 256, 0, stream>>>(x, rnorm, xh, N, 1);
    prep_bf16<<<(M + 3) / 4, 256, 0, stream>>>(q, nullptr, qh, M, 0);
    dim3 grid(NSPLIT, M / BM);                // 64 x 8 = 512 blocks, 1/CU, 2 rounds
    nn_mfma8<<<grid, 512, 0, stream>>>(qh, xh, keys, N, nPerSplit);
  } else {
    prep_bf16<<<(N + 3) / 4, 256, 0, stream>>>(x, rnorm, nullptr, N, 1);
    dim3 gridf(NSPLIT, M / BM);               // fallback: 256-thread R13 structure
    nn_mfma_fb<<<gridf, 256, 0, stream>>>(q, x, rnorm, keys, N, nPerSplit);
  }
  finalize_kernel<<<M, 256, 0, stream>>>(keys, q, x, rnorm, y, out, nPerSplit);
}